// Round 4
// baseline (704.501 us; speedup 1.0000x reference)
//
#include <hip/hip_runtime.h>
#include <hip/hip_bf16.h>

typedef unsigned short u16;
typedef __bf16 bf16x8 __attribute__((ext_vector_type(8)));
typedef float f32x4 __attribute__((ext_vector_type(4)));

#define NROWS 32768
#define H 512
#define NS 8
#define NR 64
#define NT 12

// workspace layout (bytes)
#define WS_W1T   0            // [8][512 n][512 k] bf16 = 4194304
#define WS_UCT   4194304      // [512 r][512 k] bf16    = 524288
#define WS_W2T   4718592      // [8][16 t][512 k] bf16  = 131072
#define WS_CVEC  4849664      // [8][64] f32            = 2048
#define WS_ALPH  4851712      // [8][32768] f32         = 1048576

union BFU { __bf16 h; u16 u; };
__device__ __forceinline__ u16 f2bf(float v) { BFU b; b.h = (__bf16)v; return b.u; }

__device__ __forceinline__ void gload16(const u16* g, u16* l) {
  __builtin_amdgcn_global_load_lds(
      (const __attribute__((address_space(1))) unsigned int*)g,
      (__attribute__((address_space(3))) unsigned int*)l, 16, 0, 0);
}

// ---------- prep: batched transpose + cast to bf16 ----------
__global__ __launch_bounds__(256) void transpose_cast(const float* __restrict__ in,
    u16* __restrict__ out, int Rr, int Cc, int Cpad) {
  __shared__ float tile[32][33];
  int b = blockIdx.z, r0 = blockIdx.x * 32, c0 = blockIdx.y * 32;
  int tx = threadIdx.x, ty = threadIdx.y;
#pragma unroll
  for (int i = 0; i < 4; i++) {
    int r = r0 + ty + i * 8, c = c0 + tx;
    float v = 0.f;
    if (r < Rr && c < Cc) v = in[((size_t)b * Rr + r) * Cc + c];
    tile[ty + i * 8][tx] = v;
  }
  __syncthreads();
#pragma unroll
  for (int i = 0; i < 4; i++) {
    int c = c0 + ty + i * 8, r = r0 + tx;
    if (c < Cpad && r < Rr) out[((size_t)b * Cpad + c) * Rr + r] = f2bf(tile[tx][ty + i * 8]);
  }
}

// ---------- prep: c[s][r] = sum_k mu[s][k] * Us[s][k][r] ----------
__global__ __launch_bounds__(64) void compute_c(const float* __restrict__ mu,
                                                const float* __restrict__ Us,
                                                float* __restrict__ cvec) {
  int s = blockIdx.x >> 6, r = blockIdx.x & 63, t = threadIdx.x;
  float acc = 0.f;
#pragma unroll
  for (int k = t; k < H; k += 64) acc += mu[s * H + k] * Us[((size_t)s * H + k) * NR + r];
#pragma unroll
  for (int m = 32; m; m >>= 1) acc += __shfl_xor(acc, m, 64);
  if (t == 0) cvec[blockIdx.x] = acc;
}

// ---------- routing (known-good): alphaT[s][n] ----------
__device__ __forceinline__ void stage32r(const u16* __restrict__ g, u16* l, int wave, int lane) {
#pragma unroll
  for (int i = 0; i < 8; i++) {
    int r = wave * 8 + i;
    gload16(g + (size_t)r * 512 + (size_t)((lane ^ (r & 7)) * 8), l + r * 512);
  }
}

__global__ __launch_bounds__(256, 2) void routing(
    const float* __restrict__ enc, const u16* __restrict__ UcatT,
    const float* __restrict__ cvec, float* __restrict__ alphT) {
  __shared__ __align__(16) u16 Wst[2][32 * 512];
  __shared__ float distS[NS][64];

  const int tid = threadIdx.x;
  const int wave = tid >> 6, lane = tid & 63;
  const int lnm = lane & 15, lnq = lane >> 4;
  const int row0 = blockIdx.x * 64;

  bf16x8 afrag[16];
  {
    const float* rp = enc + (size_t)(row0 + wave * 16 + lnm) * H + lnq * 8;
#pragma unroll
    for (int ks = 0; ks < 16; ks++) {
      float4 x0 = *(const float4*)(rp + ks * 32);
      float4 x1 = *(const float4*)(rp + ks * 32 + 4);
      bf16x8 a;
      a[0] = (__bf16)x0.x; a[1] = (__bf16)x0.y; a[2] = (__bf16)x0.z; a[3] = (__bf16)x0.w;
      a[4] = (__bf16)x1.x; a[5] = (__bf16)x1.y; a[6] = (__bf16)x1.z; a[7] = (__bf16)x1.w;
      afrag[ks] = a;
    }
  }

  stage32r(UcatT, Wst[0], wave, lane);
  float dsq[4] = {0.f, 0.f, 0.f, 0.f};
#pragma unroll 1
  for (int q = 0; q < 16; q++) {
    int s = q >> 1, half = q & 1;
    __syncthreads();
    if (q < 15) stage32r(UcatT + (size_t)(q + 1) * 32 * 512, Wst[(q + 1) & 1], wave, lane);
    const u16* buf = Wst[q & 1];
    f32x4 acc[2] = {};
#pragma unroll
    for (int ks = 0; ks < 16; ks++) {
      int uu = ((ks * 4 + lnq) ^ (lnm & 7)) * 8;
      bf16x8 b0 = *(const bf16x8*)&buf[lnm * 512 + uu];
      bf16x8 b1v = *(const bf16x8*)&buf[(16 + lnm) * 512 + uu];
      acc[0] = __builtin_amdgcn_mfma_f32_16x16x32_bf16(afrag[ks], b0, acc[0], 0, 0, 0);
      acc[1] = __builtin_amdgcn_mfma_f32_16x16x32_bf16(afrag[ks], b1v, acc[1], 0, 0, 0);
    }
#pragma unroll
    for (int ct = 0; ct < 2; ct++) {
      float cv = cvec[s * 64 + half * 32 + ct * 16 + lnm];
#pragma unroll
      for (int g = 0; g < 4; g++) { float d = acc[ct][g] - cv; dsq[g] += d * d; }
    }
    if (half == 1) {
#pragma unroll
      for (int m = 1; m < 16; m <<= 1) {
#pragma unroll
        for (int g = 0; g < 4; g++) dsq[g] += __shfl_xor(dsq[g], m, 16);
      }
      if (lnm == 0) {
#pragma unroll
        for (int g = 0; g < 4; g++) distS[s][wave * 16 + lnq * 4 + g] = sqrtf(dsq[g]);
      }
#pragma unroll
      for (int g = 0; g < 4; g++) dsq[g] = 0.f;
    }
  }
  __syncthreads();
  if (tid < 64) {
    float dmin = distS[0][tid];
#pragma unroll
    for (int s = 1; s < NS; s++) dmin = fminf(dmin, distS[s][tid]);
    float den = 0.f, e[NS];
#pragma unroll
    for (int s = 0; s < NS; s++) { e[s] = __expf(dmin - distS[s][tid]); den += e[s]; }
    float inv = 1.f / den;
#pragma unroll
    for (int s = 0; s < NS; s++) alphT[(size_t)s * NROWS + row0 + tid] = e[s] * inv;
  }
}

// ---------- main classifier ----------
// Round-4: TLP via 1 source per block, register-budget-correct.
// Grid: 2048 = 256 row-blocks (128 rows) x 8 sources.  sg = blockIdx&7 tends to
// pin each source's 512KB W1T slab to one XCD's L2; enc (64MB) is L3-resident.
// __launch_bounds__(256,3): VGPR cap 168 (no spill; measured use 112-128 ->
// HW may even fit 4 blocks/CU).  8 KB chunks (16 wcols x 256 K-half),
// TRIPLE-buffered, counted-vmcnt single barrier per chunk.
#define H1STR 40   // u16 row stride (80 B)

__device__ __forceinline__ void stageW8(const u16* __restrict__ g, u16* l, int tid) {
  // 16 rows x 256 u16 (512 B/row); global row stride 512 u16; XOR-swizzled 16B units
#pragma unroll
  for (int i = 0; i < 2; i++) {
    int flat = tid + i * 256;          // 0..511
    int r = flat >> 5, u = flat & 31;  // r 0..15, u 0..31
    gload16(g + (size_t)r * 512 + ((u ^ (r & 7)) * 8), l + flat * 8);
  }
}

// chunk q in [0,64): wc=q>>2, half=(q>>1)&1, kh=q&1 ; rows wc*32+half*16 .. +16
__device__ __forceinline__ const u16* chunk_base(const u16* W1g, int q) {
  return W1g + ((size_t)((q >> 2) * 32 + ((q >> 1) & 1) * 16)) * 512 + (q & 1) * 256;
}

__global__ __launch_bounds__(256, 3) void moe_main(
    const float* __restrict__ enc, const u16* __restrict__ W1T,
    const u16* __restrict__ W2T, const float* __restrict__ alphT,
    const float* __restrict__ b1g, const float* __restrict__ b2g,
    float* __restrict__ out) {
  __shared__ __align__(16) u16 Wst[3][16 * 256];   // 24576 B (triple buffer)
  __shared__ __align__(16) u16 h1c[128 * H1STR];   // 10240 B
  __shared__ float alphS[128];                     // 512 B  (total 35328 B)

  const int tid = threadIdx.x;
  const int wave = tid >> 6, lane = tid & 63;
  const int lnm = lane & 15, lnq = lane >> 4;
  const int rb = blockIdx.x >> 3, s = blockIdx.x & 7;
  const int row0 = rb * 128;

  if (tid < 128) alphS[tid] = alphT[(size_t)s * NROWS + row0 + tid];

  // b2 hoisted to prologue
  const float b2v = (lnm < NT) ? b2g[s * NT + lnm] : 0.f;

  // stationary B-operand: h0 = relu(enc) bf16, 2 tiles x 16 k-steps = 128 VGPR
  bf16x8 efrag[2][16];
#pragma unroll
  for (int t = 0; t < 2; t++) {
    const float* rp = enc + (size_t)(row0 + wave * 32 + t * 16 + lnm) * H + lnq * 8;
#pragma unroll
    for (int ks = 0; ks < 16; ks++) {
      float4 x0 = *(const float4*)(rp + ks * 32);
      float4 x1 = *(const float4*)(rp + ks * 32 + 4);
      bf16x8 a;
      a[0] = (__bf16)fmaxf(x0.x, 0.f); a[1] = (__bf16)fmaxf(x0.y, 0.f);
      a[2] = (__bf16)fmaxf(x0.z, 0.f); a[3] = (__bf16)fmaxf(x0.w, 0.f);
      a[4] = (__bf16)fmaxf(x1.x, 0.f); a[5] = (__bf16)fmaxf(x1.y, 0.f);
      a[6] = (__bf16)fmaxf(x1.z, 0.f); a[7] = (__bf16)fmaxf(x1.w, 0.f);
      efrag[t][ks] = a;
    }
  }

  // make alphS writes visible before switching to raw s_barrier sync
  __syncthreads();

  const u16* W1g = W1T + (size_t)s * 512 * 512;
  stageW8(chunk_base(W1g, 0), Wst[0], tid);
  int cb = 0;
  f32x4 acc[2][2];
  f32x4 oacc[2] = {};
#pragma unroll 1
  for (int wc = 0; wc < 16; wc++) {
    // hoisted epilogue operands (issued EARLY; older than the staged prefetch)
    float4 bq0 = *(const float4*)&b1g[s * H + wc * 32 + lnq * 4];
    float4 bq1 = *(const float4*)&b1g[s * H + wc * 32 + 16 + lnq * 4];
    bf16x8 bw = *(const bf16x8*)&W2T[((size_t)s * 16 + lnm) * H + wc * 32 + lnq * 8];
#pragma unroll
    for (int t = 0; t < 2; t++) { acc[t][0] = (f32x4){0,0,0,0}; acc[t][1] = (f32x4){0,0,0,0}; }
#pragma unroll
    for (int half = 0; half < 2; half++) {
#pragma unroll
      for (int kh = 0; kh < 2; kh++) {
        const int q = wc * 4 + half * 2 + kh;
        const int nb = (cb == 2) ? 0 : cb + 1;
        if (q + 1 < 64) {
          stageW8(chunk_base(W1g, q + 1), Wst[nb], tid);
          asm volatile("s_waitcnt vmcnt(2)" ::: "memory");  // own stage(q) retired
        } else {
          asm volatile("s_waitcnt vmcnt(0)" ::: "memory");  // last chunk: drain
        }
        __builtin_amdgcn_s_barrier();                        // all stage(q) visible
        const u16* buf = Wst[cb];
        __builtin_amdgcn_s_setprio(1);
#pragma unroll
        for (int ksl = 0; ksl < 8; ksl++) {
          const int uu = ((ksl * 4 + lnq) ^ (lnm & 7)) * 8;
          bf16x8 w = *(const bf16x8*)&buf[lnm * 256 + uu];
#pragma unroll
          for (int t = 0; t < 2; t++)
            acc[t][half] = __builtin_amdgcn_mfma_f32_16x16x32_bf16(
                w, efrag[t][kh * 8 + ksl], acc[t][half], 0, 0, 0);
        }
        __builtin_amdgcn_s_setprio(0);
        cb = nb;
      }
    }
    // ---- epilogue: h1 = relu(acc + b1) -> wave-private h1c rows (packed b64) ----
#pragma unroll
    for (int ct = 0; ct < 2; ct++) {
      float4 bq = ct ? bq1 : bq0;
#pragma unroll
      for (int t = 0; t < 2; t++) {
        union { u16 u[4]; uint2 v; } pk;
        pk.u[0] = f2bf(fmaxf(acc[t][ct][0] + bq.x, 0.f));
        pk.u[1] = f2bf(fmaxf(acc[t][ct][1] + bq.y, 0.f));
        pk.u[2] = f2bf(fmaxf(acc[t][ct][2] + bq.z, 0.f));
        pk.u[3] = f2bf(fmaxf(acc[t][ct][3] + bq.w, 0.f));
        *(uint2*)&h1c[(wave * 32 + t * 16 + lnm) * H1STR + ct * 16 + lnq * 4] = pk.v;
      }
    }
    // ---- GEMM2 partial over this 32-wcol window (wave-private, no barrier) ----
    {
#pragma unroll
      for (int t = 0; t < 2; t++) {
        bf16x8 a2 = *(const bf16x8*)&h1c[(wave * 32 + t * 16 + lnm) * H1STR + lnq * 8];
        oacc[t] = __builtin_amdgcn_mfma_f32_16x16x32_bf16(a2, bw, oacc[t], 0, 0, 0);
      }
    }
  }
  // ---- sigmoid + alpha-weighted accumulate, combine across 8 source-blocks ----
  if (lnm < NT) {
#pragma unroll
    for (int t = 0; t < 2; t++) {
#pragma unroll
      for (int g = 0; g < 4; g++) {
        float sig = 1.f / (1.f + __expf(-(oacc[t][g] + b2v)));
        float v = alphS[wave * 32 + t * 16 + lnq * 4 + g] * sig;
        int rg = row0 + wave * 32 + t * 16 + lnq * 4 + g;
        atomicAdd(&out[(size_t)rg * NT + lnm], v);
      }
    }
  }
}

extern "C" void kernel_launch(void* const* d_in, const int* in_sizes, int n_in,
                              void* d_out, int out_size, void* d_ws, size_t ws_size,
                              hipStream_t stream) {
  const float* enc = (const float*)d_in[0];
  const float* mu  = (const float*)d_in[1];
  const float* Us  = (const float*)d_in[2];
  const float* W1  = (const float*)d_in[3];
  const float* b1  = (const float*)d_in[4];
  const float* W2  = (const float*)d_in[5];
  const float* b2  = (const float*)d_in[6];
  float* out = (float*)d_out;
  char* ws = (char*)d_ws;
  u16* W1T    = (u16*)(ws + WS_W1T);
  u16* UcatT  = (u16*)(ws + WS_UCT);
  u16* W2T    = (u16*)(ws + WS_W2T);
  float* cvec = (float*)(ws + WS_CVEC);
  float* alphT = (float*)(ws + WS_ALPH);

  dim3 tb(32, 8, 1);
  transpose_cast<<<dim3(16, 16, 8), tb, 0, stream>>>(W1, W1T, 512, 512, 512);
  transpose_cast<<<dim3(16, 2, 8),  tb, 0, stream>>>(Us, UcatT, 512, 64, 64);
  transpose_cast<<<dim3(16, 1, 8),  tb, 0, stream>>>(W2, W2T, 512, 12, 16);
  compute_c<<<512, 64, 0, stream>>>(mu, Us, cvec);
  routing<<<512, 256, 0, stream>>>(enc, UcatT, cvec, alphT);
  hipMemsetAsync(out, 0, (size_t)out_size * sizeof(float), stream);
  moe_main<<<2048, 256, 0, stream>>>(enc, W1T, W2T, alphT, b1, b2, out);
}

// Round 5
// 369.239 us; speedup vs baseline: 1.9080x; 1.9080x over previous
//
#include <hip/hip_runtime.h>
#include <hip/hip_bf16.h>

typedef unsigned short u16;
typedef __bf16 bf16x8 __attribute__((ext_vector_type(8)));
typedef float f32x4 __attribute__((ext_vector_type(4)));

#define NROWS 32768
#define H 512
#define NS 8
#define NR 64
#define NT 12

// workspace layout (bytes)
#define WS_W1T   0            // [8][512 n][512 k] bf16 = 4194304
#define WS_UCT   4194304      // [512 r][512 k] bf16    = 524288
#define WS_W2T   4718592      // [8][16 t][512 k] bf16  = 131072
#define WS_CVEC  4849664      // [8][64] f32            = 2048
#define WS_ALPH  4851712      // [8][32768] f32         = 1048576

union BFU { __bf16 h; u16 u; };
__device__ __forceinline__ u16 f2bf(float v) { BFU b; b.h = (__bf16)v; return b.u; }

__device__ __forceinline__ void gload16(const u16* g, u16* l) {
  __builtin_amdgcn_global_load_lds(
      (const __attribute__((address_space(1))) unsigned int*)g,
      (__attribute__((address_space(3))) unsigned int*)l, 16, 0, 0);
}

// ---------- prep: batched transpose + cast to bf16 ----------
__global__ __launch_bounds__(256) void transpose_cast(const float* __restrict__ in,
    u16* __restrict__ out, int Rr, int Cc, int Cpad) {
  __shared__ float tile[32][33];
  int b = blockIdx.z, r0 = blockIdx.x * 32, c0 = blockIdx.y * 32;
  int tx = threadIdx.x, ty = threadIdx.y;
#pragma unroll
  for (int i = 0; i < 4; i++) {
    int r = r0 + ty + i * 8, c = c0 + tx;
    float v = 0.f;
    if (r < Rr && c < Cc) v = in[((size_t)b * Rr + r) * Cc + c];
    tile[ty + i * 8][tx] = v;
  }
  __syncthreads();
#pragma unroll
  for (int i = 0; i < 4; i++) {
    int c = c0 + ty + i * 8, r = r0 + tx;
    if (c < Cpad && r < Rr) out[((size_t)b * Cpad + c) * Rr + r] = f2bf(tile[tx][ty + i * 8]);
  }
}

// ---------- prep: c[s][r] = sum_k mu[s][k] * Us[s][k][r] ----------
__global__ __launch_bounds__(64) void compute_c(const float* __restrict__ mu,
                                                const float* __restrict__ Us,
                                                float* __restrict__ cvec) {
  int s = blockIdx.x >> 6, r = blockIdx.x & 63, t = threadIdx.x;
  float acc = 0.f;
#pragma unroll
  for (int k = t; k < H; k += 64) acc += mu[s * H + k] * Us[((size_t)s * H + k) * NR + r];
#pragma unroll
  for (int m = 32; m; m >>= 1) acc += __shfl_xor(acc, m, 64);
  if (t == 0) cvec[blockIdx.x] = acc;
}

// ---------- routing (known-good): alphaT[s][n] ----------
__device__ __forceinline__ void stage32r(const u16* __restrict__ g, u16* l, int wave, int lane) {
#pragma unroll
  for (int i = 0; i < 8; i++) {
    int r = wave * 8 + i;
    gload16(g + (size_t)r * 512 + (size_t)((lane ^ (r & 7)) * 8), l + r * 512);
  }
}

__global__ __launch_bounds__(256, 2) void routing(
    const float* __restrict__ enc, const u16* __restrict__ UcatT,
    const float* __restrict__ cvec, float* __restrict__ alphT) {
  __shared__ __align__(16) u16 Wst[2][32 * 512];
  __shared__ float distS[NS][64];

  const int tid = threadIdx.x;
  const int wave = tid >> 6, lane = tid & 63;
  const int lnm = lane & 15, lnq = lane >> 4;
  const int row0 = blockIdx.x * 64;

  bf16x8 afrag[16];
  {
    const float* rp = enc + (size_t)(row0 + wave * 16 + lnm) * H + lnq * 8;
#pragma unroll
    for (int ks = 0; ks < 16; ks++) {
      float4 x0 = *(const float4*)(rp + ks * 32);
      float4 x1 = *(const float4*)(rp + ks * 32 + 4);
      bf16x8 a;
      a[0] = (__bf16)x0.x; a[1] = (__bf16)x0.y; a[2] = (__bf16)x0.z; a[3] = (__bf16)x0.w;
      a[4] = (__bf16)x1.x; a[5] = (__bf16)x1.y; a[6] = (__bf16)x1.z; a[7] = (__bf16)x1.w;
      afrag[ks] = a;
    }
  }

  stage32r(UcatT, Wst[0], wave, lane);
  float dsq[4] = {0.f, 0.f, 0.f, 0.f};
#pragma unroll 1
  for (int q = 0; q < 16; q++) {
    int s = q >> 1, half = q & 1;
    __syncthreads();
    if (q < 15) stage32r(UcatT + (size_t)(q + 1) * 32 * 512, Wst[(q + 1) & 1], wave, lane);
    const u16* buf = Wst[q & 1];
    f32x4 acc[2] = {};
#pragma unroll
    for (int ks = 0; ks < 16; ks++) {
      int uu = ((ks * 4 + lnq) ^ (lnm & 7)) * 8;
      bf16x8 b0 = *(const bf16x8*)&buf[lnm * 512 + uu];
      bf16x8 b1v = *(const bf16x8*)&buf[(16 + lnm) * 512 + uu];
      acc[0] = __builtin_amdgcn_mfma_f32_16x16x32_bf16(afrag[ks], b0, acc[0], 0, 0, 0);
      acc[1] = __builtin_amdgcn_mfma_f32_16x16x32_bf16(afrag[ks], b1v, acc[1], 0, 0, 0);
    }
#pragma unroll
    for (int ct = 0; ct < 2; ct++) {
      float cv = cvec[s * 64 + half * 32 + ct * 16 + lnm];
#pragma unroll
      for (int g = 0; g < 4; g++) { float d = acc[ct][g] - cv; dsq[g] += d * d; }
    }
    if (half == 1) {
#pragma unroll
      for (int m = 1; m < 16; m <<= 1) {
#pragma unroll
        for (int g = 0; g < 4; g++) dsq[g] += __shfl_xor(dsq[g], m, 16);
      }
      if (lnm == 0) {
#pragma unroll
        for (int g = 0; g < 4; g++) distS[s][wave * 16 + lnq * 4 + g] = sqrtf(dsq[g]);
      }
#pragma unroll
      for (int g = 0; g < 4; g++) dsq[g] = 0.f;
    }
  }
  __syncthreads();
  if (tid < 64) {
    float dmin = distS[0][tid];
#pragma unroll
    for (int s = 1; s < NS; s++) dmin = fminf(dmin, distS[s][tid]);
    float den = 0.f, e[NS];
#pragma unroll
    for (int s = 0; s < NS; s++) { e[s] = __expf(dmin - distS[s][tid]); den += e[s]; }
    float inv = 1.f / den;
#pragma unroll
    for (int s = 0; s < NS; s++) alphT[(size_t)s * NROWS + row0 + tid] = e[s] * inv;
  }
}

// ---------- main classifier ----------
// Round-5: round-4 structure (1 source/block, grid 2048, LDS 35328 B) with the
// PROVEN allocator setting __launch_bounds__(256,2).  Occupancy is decided by
// actual resources: VGPR=128 -> 4 waves/SIMD; LDS 35328 -> 4 blocks/CU.
// (Round 4's (256,3) made the allocator target 6 waves/EU -> 84 VGPR + scratch
// spill of the 128-reg stationary efrag -> 1.9 GB HBM spill traffic.  Never
// raise min-waves on a reg-stationary kernel.)
// 8 KB chunks (16 wcols x 256 K-half), TRIPLE-buffered, counted-vmcnt single
// barrier per chunk; s = blockIdx&7 matches round-robin XCD assignment so each
// XCD keeps one source's 512 KB W1T slab L2-resident.
#define H1STR 40   // u16 row stride (80 B)

__device__ __forceinline__ void stageW8(const u16* __restrict__ g, u16* l, int tid) {
  // 16 rows x 256 u16 (512 B/row); global row stride 512 u16; XOR-swizzled 16B units
#pragma unroll
  for (int i = 0; i < 2; i++) {
    int flat = tid + i * 256;          // 0..511
    int r = flat >> 5, u = flat & 31;  // r 0..15, u 0..31
    gload16(g + (size_t)r * 512 + ((u ^ (r & 7)) * 8), l + flat * 8);
  }
}

// chunk q in [0,64): wc=q>>2, half=(q>>1)&1, kh=q&1 ; rows wc*32+half*16 .. +16
__device__ __forceinline__ const u16* chunk_base(const u16* W1g, int q) {
  return W1g + ((size_t)((q >> 2) * 32 + ((q >> 1) & 1) * 16)) * 512 + (q & 1) * 256;
}

__global__ __launch_bounds__(256, 2) void moe_main(
    const float* __restrict__ enc, const u16* __restrict__ W1T,
    const u16* __restrict__ W2T, const float* __restrict__ alphT,
    const float* __restrict__ b1g, const float* __restrict__ b2g,
    float* __restrict__ out) {
  __shared__ __align__(16) u16 Wst[3][16 * 256];   // 24576 B (triple buffer)
  __shared__ __align__(16) u16 h1c[128 * H1STR];   // 10240 B
  __shared__ float alphS[128];                     // 512 B  (total 35328 B)

  const int tid = threadIdx.x;
  const int wave = tid >> 6, lane = tid & 63;
  const int lnm = lane & 15, lnq = lane >> 4;
  const int rb = blockIdx.x >> 3, s = blockIdx.x & 7;
  const int row0 = rb * 128;

  if (tid < 128) alphS[tid] = alphT[(size_t)s * NROWS + row0 + tid];

  // b2 hoisted to prologue
  const float b2v = (lnm < NT) ? b2g[s * NT + lnm] : 0.f;

  // stationary B-operand: h0 = relu(enc) bf16, 2 tiles x 16 k-steps = 128 VGPR
  bf16x8 efrag[2][16];
#pragma unroll
  for (int t = 0; t < 2; t++) {
    const float* rp = enc + (size_t)(row0 + wave * 32 + t * 16 + lnm) * H + lnq * 8;
#pragma unroll
    for (int ks = 0; ks < 16; ks++) {
      float4 x0 = *(const float4*)(rp + ks * 32);
      float4 x1 = *(const float4*)(rp + ks * 32 + 4);
      bf16x8 a;
      a[0] = (__bf16)fmaxf(x0.x, 0.f); a[1] = (__bf16)fmaxf(x0.y, 0.f);
      a[2] = (__bf16)fmaxf(x0.z, 0.f); a[3] = (__bf16)fmaxf(x0.w, 0.f);
      a[4] = (__bf16)fmaxf(x1.x, 0.f); a[5] = (__bf16)fmaxf(x1.y, 0.f);
      a[6] = (__bf16)fmaxf(x1.z, 0.f); a[7] = (__bf16)fmaxf(x1.w, 0.f);
      efrag[t][ks] = a;
    }
  }

  // make alphS writes visible before switching to raw s_barrier sync
  __syncthreads();

  const u16* W1g = W1T + (size_t)s * 512 * 512;
  stageW8(chunk_base(W1g, 0), Wst[0], tid);
  int cb = 0;
  f32x4 acc[2][2];
  f32x4 oacc[2] = {};
#pragma unroll 1
  for (int wc = 0; wc < 16; wc++) {
    // hoisted epilogue operands (issued EARLY; older than the staged prefetch)
    float4 bq0 = *(const float4*)&b1g[s * H + wc * 32 + lnq * 4];
    float4 bq1 = *(const float4*)&b1g[s * H + wc * 32 + 16 + lnq * 4];
    bf16x8 bw = *(const bf16x8*)&W2T[((size_t)s * 16 + lnm) * H + wc * 32 + lnq * 8];
#pragma unroll
    for (int t = 0; t < 2; t++) { acc[t][0] = (f32x4){0,0,0,0}; acc[t][1] = (f32x4){0,0,0,0}; }
#pragma unroll
    for (int half = 0; half < 2; half++) {
#pragma unroll
      for (int kh = 0; kh < 2; kh++) {
        const int q = wc * 4 + half * 2 + kh;
        const int nb = (cb == 2) ? 0 : cb + 1;
        if (q + 1 < 64) {
          stageW8(chunk_base(W1g, q + 1), Wst[nb], tid);
          asm volatile("s_waitcnt vmcnt(2)" ::: "memory");  // own stage(q) retired
        } else {
          asm volatile("s_waitcnt vmcnt(0)" ::: "memory");  // last chunk: drain
        }
        __builtin_amdgcn_s_barrier();                        // all stage(q) visible
        const u16* buf = Wst[cb];
        __builtin_amdgcn_s_setprio(1);
#pragma unroll
        for (int ksl = 0; ksl < 8; ksl++) {
          const int uu = ((ksl * 4 + lnq) ^ (lnm & 7)) * 8;
          bf16x8 w = *(const bf16x8*)&buf[lnm * 256 + uu];
#pragma unroll
          for (int t = 0; t < 2; t++)
            acc[t][half] = __builtin_amdgcn_mfma_f32_16x16x32_bf16(
                w, efrag[t][kh * 8 + ksl], acc[t][half], 0, 0, 0);
        }
        __builtin_amdgcn_s_setprio(0);
        cb = nb;
      }
    }
    // ---- epilogue: h1 = relu(acc + b1) -> wave-private h1c rows (packed b64) ----
#pragma unroll
    for (int ct = 0; ct < 2; ct++) {
      float4 bq = ct ? bq1 : bq0;
#pragma unroll
      for (int t = 0; t < 2; t++) {
        union { u16 u[4]; uint2 v; } pk;
        pk.u[0] = f2bf(fmaxf(acc[t][ct][0] + bq.x, 0.f));
        pk.u[1] = f2bf(fmaxf(acc[t][ct][1] + bq.y, 0.f));
        pk.u[2] = f2bf(fmaxf(acc[t][ct][2] + bq.z, 0.f));
        pk.u[3] = f2bf(fmaxf(acc[t][ct][3] + bq.w, 0.f));
        *(uint2*)&h1c[(wave * 32 + t * 16 + lnm) * H1STR + ct * 16 + lnq * 4] = pk.v;
      }
    }
    // ---- GEMM2 partial over this 32-wcol window (wave-private, no barrier) ----
    {
#pragma unroll
      for (int t = 0; t < 2; t++) {
        bf16x8 a2 = *(const bf16x8*)&h1c[(wave * 32 + t * 16 + lnm) * H1STR + lnq * 8];
        oacc[t] = __builtin_amdgcn_mfma_f32_16x16x32_bf16(a2, bw, oacc[t], 0, 0, 0);
      }
    }
  }
  // ---- sigmoid + alpha-weighted accumulate, combine across 8 source-blocks ----
  if (lnm < NT) {
#pragma unroll
    for (int t = 0; t < 2; t++) {
#pragma unroll
      for (int g = 0; g < 4; g++) {
        float sig = 1.f / (1.f + __expf(-(oacc[t][g] + b2v)));
        float v = alphS[wave * 32 + t * 16 + lnq * 4 + g] * sig;
        int rg = row0 + wave * 32 + t * 16 + lnq * 4 + g;
        atomicAdd(&out[(size_t)rg * NT + lnm], v);
      }
    }
  }
}

extern "C" void kernel_launch(void* const* d_in, const int* in_sizes, int n_in,
                              void* d_out, int out_size, void* d_ws, size_t ws_size,
                              hipStream_t stream) {
  const float* enc = (const float*)d_in[0];
  const float* mu  = (const float*)d_in[1];
  const float* Us  = (const float*)d_in[2];
  const float* W1  = (const float*)d_in[3];
  const float* b1  = (const float*)d_in[4];
  const float* W2  = (const float*)d_in[5];
  const float* b2  = (const float*)d_in[6];
  float* out = (float*)d_out;
  char* ws = (char*)d_ws;
  u16* W1T    = (u16*)(ws + WS_W1T);
  u16* UcatT  = (u16*)(ws + WS_UCT);
  u16* W2T    = (u16*)(ws + WS_W2T);
  float* cvec = (float*)(ws + WS_CVEC);
  float* alphT = (float*)(ws + WS_ALPH);

  dim3 tb(32, 8, 1);
  transpose_cast<<<dim3(16, 16, 8), tb, 0, stream>>>(W1, W1T, 512, 512, 512);
  transpose_cast<<<dim3(16, 2, 8),  tb, 0, stream>>>(Us, UcatT, 512, 64, 64);
  transpose_cast<<<dim3(16, 1, 8),  tb, 0, stream>>>(W2, W2T, 512, 12, 16);
  compute_c<<<512, 64, 0, stream>>>(mu, Us, cvec);
  routing<<<512, 256, 0, stream>>>(enc, UcatT, cvec, alphT);
  hipMemsetAsync(out, 0, (size_t)out_size * sizeof(float), stream);
  moe_main<<<2048, 256, 0, stream>>>(enc, W1T, W2T, alphT, b1, b2, out);
}

// Round 6
// 289.610 us; speedup vs baseline: 2.4326x; 1.2750x over previous
//
#include <hip/hip_runtime.h>
#include <hip/hip_bf16.h>

typedef unsigned short u16;
typedef __bf16 bf16x8 __attribute__((ext_vector_type(8)));
typedef float f32x4 __attribute__((ext_vector_type(4)));

#define NROWS 32768
#define H 512
#define NS 8
#define NR 64
#define NT 12

// workspace layout (bytes)
#define WS_W1T   0            // [8][512 n][512 k] bf16 = 4194304
#define WS_UCT   4194304      // [512 r][512 k] bf16    = 524288
#define WS_W2T   4718592      // [8][16 t][512 k] bf16  = 131072
#define WS_CVEC  4849664      // [8][64] f32            = 2048
#define WS_ALPH  4851712      // [8][32768] f32         = 1048576

union BFU { __bf16 h; u16 u; };
__device__ __forceinline__ u16 f2bf(float v) { BFU b; b.h = (__bf16)v; return b.u; }

__device__ __forceinline__ void gload16(const u16* g, u16* l) {
  __builtin_amdgcn_global_load_lds(
      (const __attribute__((address_space(1))) unsigned int*)g,
      (__attribute__((address_space(3))) unsigned int*)l, 16, 0, 0);
}

// ---------- prep: batched transpose + cast to bf16 ----------
__global__ __launch_bounds__(256) void transpose_cast(const float* __restrict__ in,
    u16* __restrict__ out, int Rr, int Cc, int Cpad) {
  __shared__ float tile[32][33];
  int b = blockIdx.z, r0 = blockIdx.x * 32, c0 = blockIdx.y * 32;
  int tx = threadIdx.x, ty = threadIdx.y;
#pragma unroll
  for (int i = 0; i < 4; i++) {
    int r = r0 + ty + i * 8, c = c0 + tx;
    float v = 0.f;
    if (r < Rr && c < Cc) v = in[((size_t)b * Rr + r) * Cc + c];
    tile[ty + i * 8][tx] = v;
  }
  __syncthreads();
#pragma unroll
  for (int i = 0; i < 4; i++) {
    int c = c0 + ty + i * 8, r = r0 + tx;
    if (c < Cpad && r < Rr) out[((size_t)b * Cpad + c) * Rr + r] = f2bf(tile[tx][ty + i * 8]);
  }
}

// ---------- prep: c[s][r] = sum_k mu[s][k] * Us[s][k][r] ----------
__global__ __launch_bounds__(64) void compute_c(const float* __restrict__ mu,
                                                const float* __restrict__ Us,
                                                float* __restrict__ cvec) {
  int s = blockIdx.x >> 6, r = blockIdx.x & 63, t = threadIdx.x;
  float acc = 0.f;
#pragma unroll
  for (int k = t; k < H; k += 64) acc += mu[s * H + k] * Us[((size_t)s * H + k) * NR + r];
#pragma unroll
  for (int m = 32; m; m >>= 1) acc += __shfl_xor(acc, m, 64);
  if (t == 0) cvec[blockIdx.x] = acc;
}

// ---------- shared staging helper: 32 rows x 256 u16, src row stride 512 ----------
__device__ __forceinline__ void stageW16(const u16* __restrict__ g, u16* l, int tid) {
#pragma unroll
  for (int i = 0; i < 4; i++) {
    int flat = tid + i * 256;          // 0..1023
    int r = flat >> 5, u = flat & 31;
    gload16(g + (size_t)r * 512 + (u ^ (r & 7)) * 8, l + flat * 8);
  }
}

// ---------- routing: rebuilt on the moe_main template ----------
// 256 blocks x 128 rows, t=2 reuse (16 LDS reads / 32 MFMAs per phase),
// 16 KB chunks (32 rcols x 256 K) triple-buffered, counted-vmcnt single
// barrier; cvec pre-staged in LDS so the loop has NO non-stage VMEM.
__global__ __launch_bounds__(256, 2) void routing(
    const float* __restrict__ enc, const u16* __restrict__ UcatT,
    const float* __restrict__ cvec, float* __restrict__ alphT) {
  __shared__ __align__(16) u16 Wst[3][32 * 256];   // 49152 B
  __shared__ float distS[NS][128];                 // 4096 B
  __shared__ float cvS[512];                       // 2048 B (total 55296)

  const int tid = threadIdx.x;
  const int wave = tid >> 6, lane = tid & 63;
  const int lnm = lane & 15, lnq = lane >> 4;
  const int row0 = blockIdx.x * 128;

  cvS[tid] = cvec[tid];
  cvS[256 + tid] = cvec[256 + tid];

  // stationary A-operand: raw enc (no relu), 2 tiles x 16 k-steps = 128 VGPR
  bf16x8 afrag[2][16];
#pragma unroll
  for (int t = 0; t < 2; t++) {
    const float* rp = enc + (size_t)(row0 + wave * 32 + t * 16 + lnm) * H + lnq * 8;
#pragma unroll
    for (int ks = 0; ks < 16; ks++) {
      float4 x0 = *(const float4*)(rp + ks * 32);
      float4 x1 = *(const float4*)(rp + ks * 32 + 4);
      bf16x8 a;
      a[0] = (__bf16)x0.x; a[1] = (__bf16)x0.y; a[2] = (__bf16)x0.z; a[3] = (__bf16)x0.w;
      a[4] = (__bf16)x1.x; a[5] = (__bf16)x1.y; a[6] = (__bf16)x1.z; a[7] = (__bf16)x1.w;
      afrag[t][ks] = a;
    }
  }

  __syncthreads();   // cvS visible before raw-barrier loop

  stageW16(UcatT, Wst[0], tid);   // q=0: rcols 0..31, K 0..255
  int cb = 0;
  f32x4 acc[2][2];
  float dsq[2][4] = {};
#pragma unroll 1
  for (int wc = 0; wc < 16; wc++) {
#pragma unroll
    for (int t = 0; t < 2; t++) { acc[t][0] = (f32x4){0,0,0,0}; acc[t][1] = (f32x4){0,0,0,0}; }
#pragma unroll
    for (int kh = 0; kh < 2; kh++) {
      const int q = wc * 2 + kh;
      const int nb = (cb == 2) ? 0 : cb + 1;
      if (q + 1 < 32) {
        stageW16(UcatT + (size_t)((q + 1) >> 1) * 32 * 512 + ((q + 1) & 1) * 256, Wst[nb], tid);
        asm volatile("s_waitcnt vmcnt(4)" ::: "memory");  // own stage(q) retired
      } else {
        asm volatile("s_waitcnt vmcnt(0)" ::: "memory");
      }
      __builtin_amdgcn_s_barrier();
      const u16* buf = Wst[cb];
      __builtin_amdgcn_s_setprio(1);
#pragma unroll
      for (int ksl = 0; ksl < 8; ksl++) {
        const int uu = ((ksl * 4 + lnq) ^ (lnm & 7)) * 8;
        bf16x8 b0 = *(const bf16x8*)&buf[lnm * 256 + uu];
        bf16x8 b1v = *(const bf16x8*)&buf[(16 + lnm) * 256 + uu];
#pragma unroll
        for (int t = 0; t < 2; t++) {
          acc[t][0] = __builtin_amdgcn_mfma_f32_16x16x32_bf16(afrag[t][kh * 8 + ksl], b0, acc[t][0], 0, 0, 0);
          acc[t][1] = __builtin_amdgcn_mfma_f32_16x16x32_bf16(afrag[t][kh * 8 + ksl], b1v, acc[t][1], 0, 0, 0);
        }
      }
      __builtin_amdgcn_s_setprio(0);
      cb = nb;
    }
    // dsq accumulation over this 32-rcol window (rcols wc*32 + ct*16 + lnm)
#pragma unroll
    for (int ct = 0; ct < 2; ct++) {
      float cv = cvS[wc * 32 + ct * 16 + lnm];
#pragma unroll
      for (int t = 0; t < 2; t++)
#pragma unroll
        for (int g = 0; g < 4; g++) { float d = acc[t][ct][g] - cv; dsq[t][g] += d * d; }
    }
    if (wc & 1) {   // source s = wc>>1 complete (64 rcols)
#pragma unroll
      for (int m = 1; m < 16; m <<= 1) {
#pragma unroll
        for (int t = 0; t < 2; t++)
#pragma unroll
          for (int g = 0; g < 4; g++) dsq[t][g] += __shfl_xor(dsq[t][g], m, 16);
      }
      if (lnm == 0) {
#pragma unroll
        for (int t = 0; t < 2; t++)
#pragma unroll
          for (int g = 0; g < 4; g++)
            distS[wc >> 1][wave * 32 + t * 16 + lnq * 4 + g] = sqrtf(dsq[t][g]);
      }
#pragma unroll
      for (int t = 0; t < 2; t++)
#pragma unroll
        for (int g = 0; g < 4; g++) dsq[t][g] = 0.f;
    }
  }
  __syncthreads();
  if (tid < 128) {
    float dmin = distS[0][tid];
#pragma unroll
    for (int s = 1; s < NS; s++) dmin = fminf(dmin, distS[s][tid]);
    float den = 0.f, e[NS];
#pragma unroll
    for (int s = 0; s < NS; s++) { e[s] = __expf(dmin - distS[s][tid]); den += e[s]; }
    float inv = 1.f / den;
#pragma unroll
    for (int s = 0; s < NS; s++) alphT[(size_t)s * NROWS + row0 + tid] = e[s] * inv;
  }
}

// ---------- main classifier (round-1 proven structure + hoist fix) ----------
// Grid: 512 blocks = 256 row-blocks (128 rows) x 2 source-groups (4 sources).
// Triple-buffered 16 KB chunks, counted-vmcnt single barrier per half-chunk.
// NEW vs round-1: epilogue operands (b1, W2 row) issued at wc-top BEFORE the
// stages (pinned by a fence), with vmcnt(7) at kh0 / vmcnt(4) at kh1 so their
// retirement never drains the staged prefetch.  FIFO trace:
//   wc-top: [stage(q) 4] -> +bq/bw 3
//   kh0: +stage(q+1) 4 = 11 -> vmcnt(7) retires exactly stage(q)
//   kh1: +stage(q+2) 4 = 11 -> vmcnt(4) retires bq/bw + stage(q+1)
//   epilogue: bq/bw already retired; stage(q+2) stays in flight.
#define H1STR 40   // u16 row stride (80 B)

// chunk index q in [0,128): j=q>>5 (source), wc=(q>>1)&15, kh=q&1
__device__ __forceinline__ const u16* chunk_base(const u16* W1g, int q) {
  return W1g + ((size_t)(q >> 5) * 512 + ((q >> 1) & 15) * 32) * 512 + (q & 1) * 256;
}

__global__ __launch_bounds__(256, 2) void moe_main(
    const float* __restrict__ enc, const u16* __restrict__ W1T,
    const u16* __restrict__ W2T, const float* __restrict__ alphT,
    const float* __restrict__ b1g, const float* __restrict__ b2g,
    float* __restrict__ out) {
  __shared__ __align__(16) u16 Wst[3][32 * 256];   // 49152 B (triple buffer)
  __shared__ __align__(16) u16 h1c[128 * H1STR];   // 10240 B
  __shared__ float alphS[4][128];                  // 2048 B  (total 61440 B)

  const int tid = threadIdx.x;
  const int wave = tid >> 6, lane = tid & 63;
  const int lnm = lane & 15, lnq = lane >> 4;
  const int rb = blockIdx.x >> 1, sg = blockIdx.x & 1;
  const int row0 = rb * 128, sbase = sg * 4;

#pragma unroll
  for (int i = 0; i < 2; i++) {
    int u = tid + i * 256, j = u >> 7, r = u & 127;
    alphS[j][r] = alphT[(size_t)(sbase + j) * NROWS + row0 + r];
  }

  float b2v[4];
#pragma unroll
  for (int j = 0; j < 4; j++) b2v[j] = (lnm < NT) ? b2g[(sbase + j) * NT + lnm] : 0.f;

  // stationary B-operand: h0 = relu(enc) bf16, 2 tiles x 16 k-steps = 128 VGPR
  bf16x8 efrag[2][16];
#pragma unroll
  for (int t = 0; t < 2; t++) {
    const float* rp = enc + (size_t)(row0 + wave * 32 + t * 16 + lnm) * H + lnq * 8;
#pragma unroll
    for (int ks = 0; ks < 16; ks++) {
      float4 x0 = *(const float4*)(rp + ks * 32);
      float4 x1 = *(const float4*)(rp + ks * 32 + 4);
      bf16x8 a;
      a[0] = (__bf16)fmaxf(x0.x, 0.f); a[1] = (__bf16)fmaxf(x0.y, 0.f);
      a[2] = (__bf16)fmaxf(x0.z, 0.f); a[3] = (__bf16)fmaxf(x0.w, 0.f);
      a[4] = (__bf16)fmaxf(x1.x, 0.f); a[5] = (__bf16)fmaxf(x1.y, 0.f);
      a[6] = (__bf16)fmaxf(x1.z, 0.f); a[7] = (__bf16)fmaxf(x1.w, 0.f);
      efrag[t][ks] = a;
    }
  }

  // make alphS writes visible before switching to raw s_barrier sync
  __syncthreads();

  const u16* W1g = W1T + (size_t)sbase * 512 * 512;
  stageW16(chunk_base(W1g, 0), Wst[0], tid);
  int cb = 0;
  f32x4 acc[2][2];
  float fin[2][4] = {};
#pragma unroll 1
  for (int j = 0; j < 4; j++) {
    const int s = sbase + j;
    f32x4 oacc[2] = {};
#pragma unroll 1
    for (int wc = 0; wc < 16; wc++) {
      const int q = j * 32 + wc * 2;
      // hoisted epilogue operands — issued BEFORE this wc's stages
      float4 bq0 = *(const float4*)&b1g[s * H + wc * 32 + lnq * 4];
      float4 bq1 = *(const float4*)&b1g[s * H + wc * 32 + 16 + lnq * 4];
      bf16x8 bw = *(const bf16x8*)&W2T[((size_t)s * 16 + lnm) * H + wc * 32 + lnq * 8];
      asm volatile("" ::: "memory");   // pin issue order: loads stay at wc-top
      // ======== kh = 0 : compute chunk q from Wst[cb] ========
      {
        const int nb = (cb == 2) ? 0 : cb + 1;
        stageW16(chunk_base(W1g, q + 1), Wst[nb], tid);   // q+1 <= 127 always
        asm volatile("s_waitcnt vmcnt(7)" ::: "memory");  // retires stage(q); keeps bq/bw + stage(q+1)
        __builtin_amdgcn_s_barrier();
        const u16* buf = Wst[cb];
#pragma unroll
        for (int t = 0; t < 2; t++) { acc[t][0] = (f32x4){0,0,0,0}; acc[t][1] = (f32x4){0,0,0,0}; }
        __builtin_amdgcn_s_setprio(1);
#pragma unroll
        for (int ks = 0; ks < 8; ks++) {
          const int uu = ((ks * 4 + lnq) ^ (lnm & 7)) * 8;
          bf16x8 w0 = *(const bf16x8*)&buf[lnm * 256 + uu];
          bf16x8 w1 = *(const bf16x8*)&buf[(16 + lnm) * 256 + uu];
#pragma unroll
          for (int t = 0; t < 2; t++) {
            acc[t][0] = __builtin_amdgcn_mfma_f32_16x16x32_bf16(w0, efrag[t][ks], acc[t][0], 0, 0, 0);
            acc[t][1] = __builtin_amdgcn_mfma_f32_16x16x32_bf16(w1, efrag[t][ks], acc[t][1], 0, 0, 0);
          }
        }
        __builtin_amdgcn_s_setprio(0);
        cb = nb;
      }
      // ======== kh = 1 : compute chunk q+1 from Wst[cb] ========
      {
        const int nb = (cb == 2) ? 0 : cb + 1;
        if (q + 2 < 128) {
          stageW16(chunk_base(W1g, q + 2), Wst[nb], tid);
          asm volatile("s_waitcnt vmcnt(4)" ::: "memory");  // retires bq/bw + stage(q+1)
        } else {
          asm volatile("s_waitcnt vmcnt(0)" ::: "memory");  // last chunk: drain
        }
        __builtin_amdgcn_s_barrier();
        const u16* buf = Wst[cb];
        __builtin_amdgcn_s_setprio(1);
#pragma unroll
        for (int ks = 0; ks < 8; ks++) {
          const int uu = ((ks * 4 + lnq) ^ (lnm & 7)) * 8;
          bf16x8 w0 = *(const bf16x8*)&buf[lnm * 256 + uu];
          bf16x8 w1 = *(const bf16x8*)&buf[(16 + lnm) * 256 + uu];
#pragma unroll
          for (int t = 0; t < 2; t++) {
            acc[t][0] = __builtin_amdgcn_mfma_f32_16x16x32_bf16(w0, efrag[t][8 + ks], acc[t][0], 0, 0, 0);
            acc[t][1] = __builtin_amdgcn_mfma_f32_16x16x32_bf16(w1, efrag[t][8 + ks], acc[t][1], 0, 0, 0);
          }
        }
        __builtin_amdgcn_s_setprio(0);
        cb = nb;
      }
      // ---- epilogue: h1 = relu(acc + b1) -> wave-private h1c rows (packed b64) ----
#pragma unroll
      for (int ct = 0; ct < 2; ct++) {
        float4 bq = ct ? bq1 : bq0;
#pragma unroll
        for (int t = 0; t < 2; t++) {
          union { u16 u[4]; uint2 v; } pk;
          pk.u[0] = f2bf(fmaxf(acc[t][ct][0] + bq.x, 0.f));
          pk.u[1] = f2bf(fmaxf(acc[t][ct][1] + bq.y, 0.f));
          pk.u[2] = f2bf(fmaxf(acc[t][ct][2] + bq.z, 0.f));
          pk.u[3] = f2bf(fmaxf(acc[t][ct][3] + bq.w, 0.f));
          *(uint2*)&h1c[(wave * 32 + t * 16 + lnm) * H1STR + ct * 16 + lnq * 4] = pk.v;
        }
      }
      // ---- GEMM2 partial over this 32-wcol window (wave-private, no barrier) ----
      {
#pragma unroll
        for (int t = 0; t < 2; t++) {
          bf16x8 a2 = *(const bf16x8*)&h1c[(wave * 32 + t * 16 + lnm) * H1STR + lnq * 8];
          oacc[t] = __builtin_amdgcn_mfma_f32_16x16x32_bf16(a2, bw, oacc[t], 0, 0, 0);
        }
      }
    }
    // ---- end of source: sigmoid + alpha-weighted accumulate ----
    {
#pragma unroll
      for (int t = 0; t < 2; t++) {
#pragma unroll
        for (int g = 0; g < 4; g++) {
          float sig = 1.f / (1.f + __expf(-(oacc[t][g] + b2v[j])));
          fin[t][g] += alphS[j][wave * 32 + t * 16 + lnq * 4 + g] * sig;
        }
      }
    }
  }
  // combine partials across the 2 source-groups
  if (lnm < NT) {
#pragma unroll
    for (int t = 0; t < 2; t++) {
#pragma unroll
      for (int g = 0; g < 4; g++) {
        int rg = row0 + wave * 32 + t * 16 + lnq * 4 + g;
        atomicAdd(&out[(size_t)rg * NT + lnm], fin[t][g]);
      }
    }
  }
}

extern "C" void kernel_launch(void* const* d_in, const int* in_sizes, int n_in,
                              void* d_out, int out_size, void* d_ws, size_t ws_size,
                              hipStream_t stream) {
  const float* enc = (const float*)d_in[0];
  const float* mu  = (const float*)d_in[1];
  const float* Us  = (const float*)d_in[2];
  const float* W1  = (const float*)d_in[3];
  const float* b1  = (const float*)d_in[4];
  const float* W2  = (const float*)d_in[5];
  const float* b2  = (const float*)d_in[6];
  float* out = (float*)d_out;
  char* ws = (char*)d_ws;
  u16* W1T    = (u16*)(ws + WS_W1T);
  u16* UcatT  = (u16*)(ws + WS_UCT);
  u16* W2T    = (u16*)(ws + WS_W2T);
  float* cvec = (float*)(ws + WS_CVEC);
  float* alphT = (float*)(ws + WS_ALPH);

  dim3 tb(32, 8, 1);
  transpose_cast<<<dim3(16, 16, 8), tb, 0, stream>>>(W1, W1T, 512, 512, 512);
  transpose_cast<<<dim3(16, 2, 8),  tb, 0, stream>>>(Us, UcatT, 512, 64, 64);
  transpose_cast<<<dim3(16, 1, 8),  tb, 0, stream>>>(W2, W2T, 512, 12, 16);
  compute_c<<<512, 64, 0, stream>>>(mu, Us, cvec);
  routing<<<256, 256, 0, stream>>>(enc, UcatT, cvec, alphT);
  hipMemsetAsync(out, 0, (size_t)out_size * sizeof(float), stream);
  moe_main<<<512, 256, 0, stream>>>(enc, W1T, W2T, alphT, b1, b2, out);
}

// Round 7
// 282.656 us; speedup vs baseline: 2.4924x; 1.0246x over previous
//
#include <hip/hip_runtime.h>
#include <hip/hip_bf16.h>

typedef unsigned short u16;
typedef __bf16 bf16x8 __attribute__((ext_vector_type(8)));
typedef float f32x4 __attribute__((ext_vector_type(4)));
typedef float f32x16 __attribute__((ext_vector_type(16)));

#define NROWS 32768
#define H 512
#define NS 8
#define NR 64
#define NT 12

// workspace layout (bytes)
#define WS_W1T   0            // [8][512 n][512 k] bf16 = 4194304
#define WS_UCT   4194304      // [512 r][512 k] bf16    = 524288
#define WS_W2T   4718592      // [8][16 t][512 k] bf16  = 131072
#define WS_CVEC  4849664      // [8][64] f32            = 2048
#define WS_ALPH  4851712      // [8][32768] f32         = 1048576

union BFU { __bf16 h; u16 u; };
__device__ __forceinline__ u16 f2bf(float v) { BFU b; b.h = (__bf16)v; return b.u; }

__device__ __forceinline__ void gload16(const u16* g, u16* l) {
  __builtin_amdgcn_global_load_lds(
      (const __attribute__((address_space(1))) unsigned int*)g,
      (__attribute__((address_space(3))) unsigned int*)l, 16, 0, 0);
}

// ---------- fused prep: 3 transposes + compute_c in one launch ----------
// blocks [0,2048): W1 transpose; [2048,2304): Us; [2304,2432): W2;
// [2432,2560): compute_c (4 waves x 1 (s,r) pair each).
__global__ __launch_bounds__(256) void prep(
    const float* __restrict__ W1, u16* __restrict__ W1T,
    const float* __restrict__ Us, u16* __restrict__ UcatT,
    const float* __restrict__ W2, u16* __restrict__ W2T,
    const float* __restrict__ mu, float* __restrict__ cvec) {
  __shared__ float tile[32][33];
  const int bid = blockIdx.x;
  const int tx = threadIdx.x, ty = threadIdx.y;
  if (bid < 2432) {
    const float* in; u16* out; int Rr, Cc, Cpad, b, r0, c0;
    if (bid < 2048) {
      in = W1; out = W1T; Rr = 512; Cc = 512; Cpad = 512;
      r0 = (bid & 15) * 32; c0 = ((bid >> 4) & 15) * 32; b = bid >> 8;
    } else if (bid < 2304) {
      int t2 = bid - 2048; in = Us; out = UcatT; Rr = 512; Cc = 64; Cpad = 64;
      r0 = (t2 & 15) * 32; c0 = ((t2 >> 4) & 1) * 32; b = t2 >> 5;
    } else {
      int t2 = bid - 2304; in = W2; out = W2T; Rr = 512; Cc = 12; Cpad = 16;
      r0 = (t2 & 15) * 32; c0 = 0; b = t2 >> 4;
    }
#pragma unroll
    for (int i = 0; i < 4; i++) {
      int r = r0 + ty + i * 8, c = c0 + tx;
      float v = 0.f;
      if (r < Rr && c < Cc) v = in[((size_t)b * Rr + r) * Cc + c];
      tile[ty + i * 8][tx] = v;
    }
    __syncthreads();
#pragma unroll
    for (int i = 0; i < 4; i++) {
      int c = c0 + ty + i * 8, r = r0 + tx;
      if (c < Cpad && r < Rr) out[((size_t)b * Cpad + c) * Rr + r] = f2bf(tile[tx][ty + i * 8]);
    }
  } else {
    const int tid = ty * 32 + tx;
    const int idx = (bid - 2432) * 4 + (tid >> 6);   // (s,r) pair, 0..511
    const int s = idx >> 6, r = idx & 63, t = tid & 63;
    float acc = 0.f;
#pragma unroll
    for (int k = t; k < H; k += 64) acc += mu[s * H + k] * Us[((size_t)s * H + k) * NR + r];
#pragma unroll
    for (int m = 32; m; m >>= 1) acc += __shfl_xor(acc, m, 64);
    if (t == 0) cvec[idx] = acc;
  }
}

// ---------- routing (round-0 known-good): alphaT[s][n] ----------
__device__ __forceinline__ void stage32r(const u16* __restrict__ g, u16* l, int wave, int lane) {
#pragma unroll
  for (int i = 0; i < 8; i++) {
    int r = wave * 8 + i;
    gload16(g + (size_t)r * 512 + (size_t)((lane ^ (r & 7)) * 8), l + r * 512);
  }
}

__global__ __launch_bounds__(256, 2) void routing(
    const float* __restrict__ enc, const u16* __restrict__ UcatT,
    const float* __restrict__ cvec, float* __restrict__ alphT) {
  __shared__ __align__(16) u16 Wst[2][32 * 512];
  __shared__ float distS[NS][64];

  const int tid = threadIdx.x;
  const int wave = tid >> 6, lane = tid & 63;
  const int lnm = lane & 15, lnq = lane >> 4;
  const int row0 = blockIdx.x * 64;

  bf16x8 afrag[16];
  {
    const float* rp = enc + (size_t)(row0 + wave * 16 + lnm) * H + lnq * 8;
#pragma unroll
    for (int ks = 0; ks < 16; ks++) {
      float4 x0 = *(const float4*)(rp + ks * 32);
      float4 x1 = *(const float4*)(rp + ks * 32 + 4);
      bf16x8 a;
      a[0] = (__bf16)x0.x; a[1] = (__bf16)x0.y; a[2] = (__bf16)x0.z; a[3] = (__bf16)x0.w;
      a[4] = (__bf16)x1.x; a[5] = (__bf16)x1.y; a[6] = (__bf16)x1.z; a[7] = (__bf16)x1.w;
      afrag[ks] = a;
    }
  }

  stage32r(UcatT, Wst[0], wave, lane);
  float dsq[4] = {0.f, 0.f, 0.f, 0.f};
#pragma unroll 1
  for (int q = 0; q < 16; q++) {
    int s = q >> 1, half = q & 1;
    __syncthreads();
    if (q < 15) stage32r(UcatT + (size_t)(q + 1) * 32 * 512, Wst[(q + 1) & 1], wave, lane);
    const u16* buf = Wst[q & 1];
    f32x4 acc[2] = {};
#pragma unroll
    for (int ks = 0; ks < 16; ks++) {
      int uu = ((ks * 4 + lnq) ^ (lnm & 7)) * 8;
      bf16x8 b0 = *(const bf16x8*)&buf[lnm * 512 + uu];
      bf16x8 b1v = *(const bf16x8*)&buf[(16 + lnm) * 512 + uu];
      acc[0] = __builtin_amdgcn_mfma_f32_16x16x32_bf16(afrag[ks], b0, acc[0], 0, 0, 0);
      acc[1] = __builtin_amdgcn_mfma_f32_16x16x32_bf16(afrag[ks], b1v, acc[1], 0, 0, 0);
    }
#pragma unroll
    for (int ct = 0; ct < 2; ct++) {
      float cv = cvec[s * 64 + half * 32 + ct * 16 + lnm];
#pragma unroll
      for (int g = 0; g < 4; g++) { float d = acc[ct][g] - cv; dsq[g] += d * d; }
    }
    if (half == 1) {
#pragma unroll
      for (int m = 1; m < 16; m <<= 1) {
#pragma unroll
        for (int g = 0; g < 4; g++) dsq[g] += __shfl_xor(dsq[g], m, 16);
      }
      if (lnm == 0) {
#pragma unroll
        for (int g = 0; g < 4; g++) distS[s][wave * 16 + lnq * 4 + g] = sqrtf(dsq[g]);
      }
#pragma unroll
      for (int g = 0; g < 4; g++) dsq[g] = 0.f;
    }
  }
  __syncthreads();
  if (tid < 64) {
    float dmin = distS[0][tid];
#pragma unroll
    for (int s = 1; s < NS; s++) dmin = fminf(dmin, distS[s][tid]);
    float den = 0.f, e[NS];
#pragma unroll
    for (int s = 0; s < NS; s++) { e[s] = __expf(dmin - distS[s][tid]); den += e[s]; }
    float inv = 1.f / den;
#pragma unroll
    for (int s = 0; s < NS; s++) alphT[(size_t)s * NROWS + row0 + tid] = e[s] * inv;
  }
}

// ---------- main classifier ----------
// Round-7: GEMM1 on 32x32x16 MFMA.  Same LDS bytes (wave reads whole chunk
// either way) but -17% MFMA pipe time (8.07 vs 2x4.85 cyc per 32k FLOP, m119)
// and half the MFMA/ds_read instruction count per kh.  Wave's 32 enc rows =
// one 32x32 output tile: A = weights (32 wcols x 16K per frag, LDS), B = enc
// regs (lane l: row l&31, k (l>>5)*8..+7), C/D: col=lane&31 = encrow,
// row=(g&3)+8*(g>>2)+4*(lane>>5) = wcol  [m74/m101 verified layout].
// Staging/counted-vmcnt/hoist machinery unchanged from round-6 (157 us).
// FIFO: wc-top 5 epi loads (4 bq + bw); kh0 +4 stage -> vmcnt(9) retires
// stage(q); kh1 +4 stage -> vmcnt(4) retires epi + stage(q+1).
#define H1STR 40   // u16 row stride (80 B)

__device__ __forceinline__ void stageW16(const u16* __restrict__ g, u16* l, int tid) {
  // 32 rows x 256 u16 (512 B/row); global row stride 512 u16; XOR-swizzled 16B units
#pragma unroll
  for (int i = 0; i < 4; i++) {
    int flat = tid + i * 256;          // 0..1023
    int r = flat >> 5, u = flat & 31;
    gload16(g + (size_t)r * 512 + (u ^ (r & 7)) * 8, l + flat * 8);
  }
}

// chunk index q in [0,128): j=q>>5 (source), wc=(q>>1)&15, kh=q&1
__device__ __forceinline__ const u16* chunk_base(const u16* W1g, int q) {
  return W1g + ((size_t)(q >> 5) * 512 + ((q >> 1) & 15) * 32) * 512 + (q & 1) * 256;
}

__global__ __launch_bounds__(256, 2) void moe_main(
    const float* __restrict__ enc, const u16* __restrict__ W1T,
    const u16* __restrict__ W2T, const float* __restrict__ alphT,
    const float* __restrict__ b1g, const float* __restrict__ b2g,
    float* __restrict__ out) {
  __shared__ __align__(16) u16 Wst[3][32 * 256];   // 49152 B (triple buffer)
  __shared__ __align__(16) u16 h1c[128 * H1STR];   // 10240 B
  __shared__ float alphS[4][128];                  // 2048 B  (total 61440 B)

  const int tid = threadIdx.x;
  const int wave = tid >> 6, lane = tid & 63;
  const int lnm = lane & 15, lnq = lane >> 4;
  const int r5 = lane & 31, hi = lane >> 5;        // 32x32 fragment coords
  const int rb = blockIdx.x >> 1, sg = blockIdx.x & 1;
  const int row0 = rb * 128, sbase = sg * 4;

#pragma unroll
  for (int i = 0; i < 2; i++) {
    int u = tid + i * 256, j = u >> 7, r = u & 127;
    alphS[j][r] = alphT[(size_t)(sbase + j) * NROWS + row0 + r];
  }

  float b2v[4];
#pragma unroll
  for (int j = 0; j < 4; j++) b2v[j] = (lnm < NT) ? b2g[(sbase + j) * NT + lnm] : 0.f;

  // stationary B-operand: h0 = relu(enc) bf16.  32x32x16 B-frag: lane l holds
  // enc row (l&31), k = ks*16 + (l>>5)*8 .. +7.  32 frags = 128 VGPR.
  bf16x8 efrag[32];
  {
    const float* rp = enc + (size_t)(row0 + wave * 32 + r5) * H + hi * 8;
#pragma unroll
    for (int ks = 0; ks < 32; ks++) {
      float4 x0 = *(const float4*)(rp + ks * 16);
      float4 x1 = *(const float4*)(rp + ks * 16 + 4);
      bf16x8 a;
      a[0] = (__bf16)fmaxf(x0.x, 0.f); a[1] = (__bf16)fmaxf(x0.y, 0.f);
      a[2] = (__bf16)fmaxf(x0.z, 0.f); a[3] = (__bf16)fmaxf(x0.w, 0.f);
      a[4] = (__bf16)fmaxf(x1.x, 0.f); a[5] = (__bf16)fmaxf(x1.y, 0.f);
      a[6] = (__bf16)fmaxf(x1.z, 0.f); a[7] = (__bf16)fmaxf(x1.w, 0.f);
      efrag[ks] = a;
    }
  }

  // make alphS writes visible before switching to raw s_barrier sync
  __syncthreads();

  const u16* W1g = W1T + (size_t)sbase * 512 * 512;
  stageW16(chunk_base(W1g, 0), Wst[0], tid);
  int cb = 0;
  float fin[2][4] = {};
#pragma unroll 1
  for (int j = 0; j < 4; j++) {
    const int s = sbase + j;
    f32x4 oacc[2] = {};
#pragma unroll 1
    for (int wc = 0; wc < 16; wc++) {
      const int q = j * 32 + wc * 2;
      // hoisted epilogue operands — issued BEFORE this wc's stages
      float4 bqv[4];
#pragma unroll
      for (int Q = 0; Q < 4; Q++)
        bqv[Q] = *(const float4*)&b1g[s * H + wc * 32 + Q * 8 + hi * 4];
      bf16x8 bw = *(const bf16x8*)&W2T[((size_t)s * 16 + lnm) * H + wc * 32 + lnq * 8];
      asm volatile("" ::: "memory");   // pin issue order: loads stay at wc-top
      f32x16 acc = {};
      // ======== kh = 0 : compute chunk q from Wst[cb] ========
      {
        const int nb = (cb == 2) ? 0 : cb + 1;
        stageW16(chunk_base(W1g, q + 1), Wst[nb], tid);   // q+1 <= 127 always
        asm volatile("s_waitcnt vmcnt(9)" ::: "memory");  // retires stage(q); keeps epi + stage(q+1)
        __builtin_amdgcn_s_barrier();
        const u16* buf = Wst[cb];
        __builtin_amdgcn_s_setprio(1);
#pragma unroll
        for (int kk = 0; kk < 16; kk++) {
          const int uu = (((kk << 1) | hi) ^ (r5 & 7)) * 8;
          bf16x8 w = *(const bf16x8*)&buf[r5 * 256 + uu];
          acc = __builtin_amdgcn_mfma_f32_32x32x16_bf16(w, efrag[kk], acc, 0, 0, 0);
        }
        __builtin_amdgcn_s_setprio(0);
        cb = nb;
      }
      // ======== kh = 1 : compute chunk q+1 from Wst[cb] ========
      {
        const int nb = (cb == 2) ? 0 : cb + 1;
        if (q + 2 < 128) {
          stageW16(chunk_base(W1g, q + 2), Wst[nb], tid);
          asm volatile("s_waitcnt vmcnt(4)" ::: "memory");  // retires epi + stage(q+1)
        } else {
          asm volatile("s_waitcnt vmcnt(0)" ::: "memory");  // last chunk: drain
        }
        __builtin_amdgcn_s_barrier();
        const u16* buf = Wst[cb];
        __builtin_amdgcn_s_setprio(1);
#pragma unroll
        for (int kk = 0; kk < 16; kk++) {
          const int uu = (((kk << 1) | hi) ^ (r5 & 7)) * 8;
          bf16x8 w = *(const bf16x8*)&buf[r5 * 256 + uu];
          acc = __builtin_amdgcn_mfma_f32_32x32x16_bf16(w, efrag[16 + kk], acc, 0, 0, 0);
        }
        __builtin_amdgcn_s_setprio(0);
        cb = nb;
      }
      // ---- epilogue: h1 = relu(acc + b1) -> h1c rows (packed b64) ----
      // lane holds encrow r5, wcols (g&3)+8*(g>>2)+4*hi: quad Q -> 4 consecutive
#pragma unroll
      for (int Q = 0; Q < 4; Q++) {
        float4 bq = bqv[Q];
        union { u16 u[4]; uint2 v; } pk;
        pk.u[0] = f2bf(fmaxf(acc[Q * 4 + 0] + bq.x, 0.f));
        pk.u[1] = f2bf(fmaxf(acc[Q * 4 + 1] + bq.y, 0.f));
        pk.u[2] = f2bf(fmaxf(acc[Q * 4 + 2] + bq.z, 0.f));
        pk.u[3] = f2bf(fmaxf(acc[Q * 4 + 3] + bq.w, 0.f));
        *(uint2*)&h1c[(wave * 32 + r5) * H1STR + Q * 8 + hi * 4] = pk.v;
      }
      // ---- GEMM2 partial over this 32-wcol window (wave-private, no barrier) ----
      {
#pragma unroll
        for (int t = 0; t < 2; t++) {
          bf16x8 a2 = *(const bf16x8*)&h1c[(wave * 32 + t * 16 + lnm) * H1STR + lnq * 8];
          oacc[t] = __builtin_amdgcn_mfma_f32_16x16x32_bf16(a2, bw, oacc[t], 0, 0, 0);
        }
      }
    }
    // ---- end of source: sigmoid + alpha-weighted accumulate ----
    {
#pragma unroll
      for (int t = 0; t < 2; t++) {
#pragma unroll
        for (int g = 0; g < 4; g++) {
          float sig = 1.f / (1.f + __expf(-(oacc[t][g] + b2v[j])));
          fin[t][g] += alphS[j][wave * 32 + t * 16 + lnq * 4 + g] * sig;
        }
      }
    }
  }
  // combine partials across the 2 source-groups
  if (lnm < NT) {
#pragma unroll
    for (int t = 0; t < 2; t++) {
#pragma unroll
      for (int g = 0; g < 4; g++) {
        int rg = row0 + wave * 32 + t * 16 + lnq * 4 + g;
        atomicAdd(&out[(size_t)rg * NT + lnm], fin[t][g]);
      }
    }
  }
}

extern "C" void kernel_launch(void* const* d_in, const int* in_sizes, int n_in,
                              void* d_out, int out_size, void* d_ws, size_t ws_size,
                              hipStream_t stream) {
  const float* enc = (const float*)d_in[0];
  const float* mu  = (const float*)d_in[1];
  const float* Us  = (const float*)d_in[2];
  const float* W1  = (const float*)d_in[3];
  const float* b1  = (const float*)d_in[4];
  const float* W2  = (const float*)d_in[5];
  const float* b2  = (const float*)d_in[6];
  float* out = (float*)d_out;
  char* ws = (char*)d_ws;
  u16* W1T    = (u16*)(ws + WS_W1T);
  u16* UcatT  = (u16*)(ws + WS_UCT);
  u16* W2T    = (u16*)(ws + WS_W2T);
  float* cvec = (float*)(ws + WS_CVEC);
  float* alphT = (float*)(ws + WS_ALPH);

  prep<<<2560, dim3(32, 8, 1), 0, stream>>>(W1, W1T, Us, UcatT, W2, W2T, mu, cvec);
  routing<<<512, 256, 0, stream>>>(enc, UcatT, cvec, alphT);
  hipMemsetAsync(out, 0, (size_t)out_size * sizeof(float), stream);
  moe_main<<<512, 256, 0, stream>>>(enc, W1T, W2T, alphT, b1, b2, out);
}

// Round 8
// 276.299 us; speedup vs baseline: 2.5498x; 1.0230x over previous
//
#include <hip/hip_runtime.h>
#include <hip/hip_bf16.h>

typedef unsigned short u16;
typedef __bf16 bf16x8 __attribute__((ext_vector_type(8)));
typedef float f32x4 __attribute__((ext_vector_type(4)));

#define NROWS 32768
#define H 512
#define NS 8
#define NR 64
#define NT 12

// workspace layout (bytes)
#define WS_W1T   0            // [8][512 n][512 k] bf16 = 4194304
#define WS_UCT   4194304      // [512 r][512 k] bf16    = 524288
#define WS_W2T   4718592      // [8][16 t][512 k] bf16  = 131072
#define WS_CVEC  4849664      // [8][64] f32            = 2048
#define WS_ALPH  4851712      // [8][32768] f32         = 1048576

union BFU { __bf16 h; u16 u; };
__device__ __forceinline__ u16 f2bf(float v) { BFU b; b.h = (__bf16)v; return b.u; }

__device__ __forceinline__ void gload16(const u16* g, u16* l) {
  __builtin_amdgcn_global_load_lds(
      (const __attribute__((address_space(1))) unsigned int*)g,
      (__attribute__((address_space(3))) unsigned int*)l, 16, 0, 0);
}

// ---------- fused prep: 3 transposes + compute_c in one launch ----------
__global__ __launch_bounds__(256) void prep(
    const float* __restrict__ W1, u16* __restrict__ W1T,
    const float* __restrict__ Us, u16* __restrict__ UcatT,
    const float* __restrict__ W2, u16* __restrict__ W2T,
    const float* __restrict__ mu, float* __restrict__ cvec) {
  __shared__ float tile[32][33];
  const int bid = blockIdx.x;
  const int tx = threadIdx.x, ty = threadIdx.y;
  if (bid < 2432) {
    const float* in; u16* out; int Rr, Cc, Cpad, b, r0, c0;
    if (bid < 2048) {
      in = W1; out = W1T; Rr = 512; Cc = 512; Cpad = 512;
      r0 = (bid & 15) * 32; c0 = ((bid >> 4) & 15) * 32; b = bid >> 8;
    } else if (bid < 2304) {
      int t2 = bid - 2048; in = Us; out = UcatT; Rr = 512; Cc = 64; Cpad = 64;
      r0 = (t2 & 15) * 32; c0 = ((t2 >> 4) & 1) * 32; b = t2 >> 5;
    } else {
      int t2 = bid - 2304; in = W2; out = W2T; Rr = 512; Cc = 12; Cpad = 16;
      r0 = (t2 & 15) * 32; c0 = 0; b = t2 >> 4;
    }
#pragma unroll
    for (int i = 0; i < 4; i++) {
      int r = r0 + ty + i * 8, c = c0 + tx;
      float v = 0.f;
      if (r < Rr && c < Cc) v = in[((size_t)b * Rr + r) * Cc + c];
      tile[ty + i * 8][tx] = v;
    }
    __syncthreads();
#pragma unroll
    for (int i = 0; i < 4; i++) {
      int c = c0 + ty + i * 8, r = r0 + tx;
      if (c < Cpad && r < Rr) out[((size_t)b * Cpad + c) * Rr + r] = f2bf(tile[tx][ty + i * 8]);
    }
  } else {
    const int tid = ty * 32 + tx;
    const int idx = (bid - 2432) * 4 + (tid >> 6);   // (s,r) pair, 0..511
    const int s = idx >> 6, r = idx & 63, t = tid & 63;
    float acc = 0.f;
#pragma unroll
    for (int k = t; k < H; k += 64) acc += mu[s * H + k] * Us[((size_t)s * H + k) * NR + r];
#pragma unroll
    for (int m = 32; m; m >>= 1) acc += __shfl_xor(acc, m, 64);
    if (t == 0) cvec[idx] = acc;
  }
}

// ---------- routing (round-0 known-good): alphaT[s][n] ----------
__device__ __forceinline__ void stage32r(const u16* __restrict__ g, u16* l, int wave, int lane) {
#pragma unroll
  for (int i = 0; i < 8; i++) {
    int r = wave * 8 + i;
    gload16(g + (size_t)r * 512 + (size_t)((lane ^ (r & 7)) * 8), l + r * 512);
  }
}

__global__ __launch_bounds__(256, 2) void routing(
    const float* __restrict__ enc, const u16* __restrict__ UcatT,
    const float* __restrict__ cvec, float* __restrict__ alphT) {
  __shared__ __align__(16) u16 Wst[2][32 * 512];
  __shared__ float distS[NS][64];

  const int tid = threadIdx.x;
  const int wave = tid >> 6, lane = tid & 63;
  const int lnm = lane & 15, lnq = lane >> 4;
  const int row0 = blockIdx.x * 64;

  bf16x8 afrag[16];
  {
    const float* rp = enc + (size_t)(row0 + wave * 16 + lnm) * H + lnq * 8;
#pragma unroll
    for (int ks = 0; ks < 16; ks++) {
      float4 x0 = *(const float4*)(rp + ks * 32);
      float4 x1 = *(const float4*)(rp + ks * 32 + 4);
      bf16x8 a;
      a[0] = (__bf16)x0.x; a[1] = (__bf16)x0.y; a[2] = (__bf16)x0.z; a[3] = (__bf16)x0.w;
      a[4] = (__bf16)x1.x; a[5] = (__bf16)x1.y; a[6] = (__bf16)x1.z; a[7] = (__bf16)x1.w;
      afrag[ks] = a;
    }
  }

  stage32r(UcatT, Wst[0], wave, lane);
  float dsq[4] = {0.f, 0.f, 0.f, 0.f};
#pragma unroll 1
  for (int q = 0; q < 16; q++) {
    int s = q >> 1, half = q & 1;
    __syncthreads();
    if (q < 15) stage32r(UcatT + (size_t)(q + 1) * 32 * 512, Wst[(q + 1) & 1], wave, lane);
    const u16* buf = Wst[q & 1];
    f32x4 acc[2] = {};
#pragma unroll
    for (int ks = 0; ks < 16; ks++) {
      int uu = ((ks * 4 + lnq) ^ (lnm & 7)) * 8;
      bf16x8 b0 = *(const bf16x8*)&buf[lnm * 512 + uu];
      bf16x8 b1v = *(const bf16x8*)&buf[(16 + lnm) * 512 + uu];
      acc[0] = __builtin_amdgcn_mfma_f32_16x16x32_bf16(afrag[ks], b0, acc[0], 0, 0, 0);
      acc[1] = __builtin_amdgcn_mfma_f32_16x16x32_bf16(afrag[ks], b1v, acc[1], 0, 0, 0);
    }
#pragma unroll
    for (int ct = 0; ct < 2; ct++) {
      float cv = cvec[s * 64 + half * 32 + ct * 16 + lnm];
#pragma unroll
      for (int g = 0; g < 4; g++) { float d = acc[ct][g] - cv; dsq[g] += d * d; }
    }
    if (half == 1) {
#pragma unroll
      for (int m = 1; m < 16; m <<= 1) {
#pragma unroll
        for (int g = 0; g < 4; g++) dsq[g] += __shfl_xor(dsq[g], m, 16);
      }
      if (lnm == 0) {
#pragma unroll
        for (int g = 0; g < 4; g++) distS[s][wave * 16 + lnq * 4 + g] = sqrtf(dsq[g]);
      }
#pragma unroll
      for (int g = 0; g < 4; g++) dsq[g] = 0.f;
    }
  }
  __syncthreads();
  if (tid < 64) {
    float dmin = distS[0][tid];
#pragma unroll
    for (int s = 1; s < NS; s++) dmin = fminf(dmin, distS[s][tid]);
    float den = 0.f, e[NS];
#pragma unroll
    for (int s = 0; s < NS; s++) { e[s] = __expf(dmin - distS[s][tid]); den += e[s]; }
    float inv = 1.f / den;
#pragma unroll
    for (int s = 0; s < NS; s++) alphT[(size_t)s * NROWS + row0 + tid] = e[s] * inv;
  }
}

// ---------- main classifier (round-6 proven 16x16 structure + wave stagger) ----------
// Grid: 512 blocks = 256 row-blocks (128 rows) x 2 source-groups (4 sources).
// Triple-buffered 16 KB chunks, counted-vmcnt single barrier per half-chunk,
// hoisted epilogue operands (vmcnt(7) kh0 / vmcnt(4) kh1) — the 157 us config.
// NEW probe: odd waves walk ks in 1^-flipped order (ks^1).  All 8 waves/CU
// otherwise issue the IDENTICAL post-barrier address sequence; ks parity sets
// the bank-quad phase ((ks&1)*4), so staggering odd waves puts concurrent
// wave-pairs on disjoint bank halves.  Both orders fully unrolled
// (compile-time efrag indices); k-sum reorder only.
#define H1STR 40   // u16 row stride (80 B)

__device__ __forceinline__ void stageW16(const u16* __restrict__ g, u16* l, int tid) {
#pragma unroll
  for (int i = 0; i < 4; i++) {
    int flat = tid + i * 256;          // 0..1023
    int r = flat >> 5, u = flat & 31;
    gload16(g + (size_t)r * 512 + (u ^ (r & 7)) * 8, l + flat * 8);
  }
}

// chunk index q in [0,128): j=q>>5 (source), wc=(q>>1)&15, kh=q&1
__device__ __forceinline__ const u16* chunk_base(const u16* W1g, int q) {
  return W1g + ((size_t)(q >> 5) * 512 + ((q >> 1) & 15) * 32) * 512 + (q & 1) * 256;
}

__global__ __launch_bounds__(256, 2) void moe_main(
    const float* __restrict__ enc, const u16* __restrict__ W1T,
    const u16* __restrict__ W2T, const float* __restrict__ alphT,
    const float* __restrict__ b1g, const float* __restrict__ b2g,
    float* __restrict__ out) {
  __shared__ __align__(16) u16 Wst[3][32 * 256];   // 49152 B (triple buffer)
  __shared__ __align__(16) u16 h1c[128 * H1STR];   // 10240 B
  __shared__ float alphS[4][128];                  // 2048 B  (total 61440 B)

  const int tid = threadIdx.x;
  const int wave = tid >> 6, lane = tid & 63;
  const int lnm = lane & 15, lnq = lane >> 4;
  const int rb = blockIdx.x >> 1, sg = blockIdx.x & 1;
  const int row0 = rb * 128, sbase = sg * 4;

#pragma unroll
  for (int i = 0; i < 2; i++) {
    int u = tid + i * 256, j = u >> 7, r = u & 127;
    alphS[j][r] = alphT[(size_t)(sbase + j) * NROWS + row0 + r];
  }

  float b2v[4];
#pragma unroll
  for (int j = 0; j < 4; j++) b2v[j] = (lnm < NT) ? b2g[(sbase + j) * NT + lnm] : 0.f;

  // stationary B-operand: h0 = relu(enc) bf16, 2 tiles x 16 k-steps = 128 VGPR
  bf16x8 efrag[2][16];
#pragma unroll
  for (int t = 0; t < 2; t++) {
    const float* rp = enc + (size_t)(row0 + wave * 32 + t * 16 + lnm) * H + lnq * 8;
#pragma unroll
    for (int ks = 0; ks < 16; ks++) {
      float4 x0 = *(const float4*)(rp + ks * 32);
      float4 x1 = *(const float4*)(rp + ks * 32 + 4);
      bf16x8 a;
      a[0] = (__bf16)fmaxf(x0.x, 0.f); a[1] = (__bf16)fmaxf(x0.y, 0.f);
      a[2] = (__bf16)fmaxf(x0.z, 0.f); a[3] = (__bf16)fmaxf(x0.w, 0.f);
      a[4] = (__bf16)fmaxf(x1.x, 0.f); a[5] = (__bf16)fmaxf(x1.y, 0.f);
      a[6] = (__bf16)fmaxf(x1.z, 0.f); a[7] = (__bf16)fmaxf(x1.w, 0.f);
      efrag[t][ks] = a;
    }
  }

  // make alphS writes visible before switching to raw s_barrier sync
  __syncthreads();

  const u16* W1g = W1T + (size_t)sbase * 512 * 512;
  stageW16(chunk_base(W1g, 0), Wst[0], tid);
  int cb = 0;
  f32x4 acc[2][2];
  float fin[2][4] = {};
  const int stg = wave & 1;   // odd waves: ks order XOR 1
#pragma unroll 1
  for (int j = 0; j < 4; j++) {
    const int s = sbase + j;
    f32x4 oacc[2] = {};
#pragma unroll 1
    for (int wc = 0; wc < 16; wc++) {
      const int q = j * 32 + wc * 2;
      // hoisted epilogue operands — issued BEFORE this wc's stages
      float4 bq0 = *(const float4*)&b1g[s * H + wc * 32 + lnq * 4];
      float4 bq1 = *(const float4*)&b1g[s * H + wc * 32 + 16 + lnq * 4];
      bf16x8 bw = *(const bf16x8*)&W2T[((size_t)s * 16 + lnm) * H + wc * 32 + lnq * 8];
      asm volatile("" ::: "memory");   // pin issue order: loads stay at wc-top
      // ======== kh = 0 : compute chunk q from Wst[cb] ========
      {
        const int nb = (cb == 2) ? 0 : cb + 1;
        stageW16(chunk_base(W1g, q + 1), Wst[nb], tid);   // q+1 <= 127 always
        asm volatile("s_waitcnt vmcnt(7)" ::: "memory");  // retires stage(q); keeps epi + stage(q+1)
        __builtin_amdgcn_s_barrier();
        const u16* buf = Wst[cb];
#pragma unroll
        for (int t = 0; t < 2; t++) { acc[t][0] = (f32x4){0,0,0,0}; acc[t][1] = (f32x4){0,0,0,0}; }
        __builtin_amdgcn_s_setprio(1);
        if (stg == 0) {
#pragma unroll
          for (int ks = 0; ks < 8; ks++) {
            const int uu = ((ks * 4 + lnq) ^ (lnm & 7)) * 8;
            bf16x8 w0 = *(const bf16x8*)&buf[lnm * 256 + uu];
            bf16x8 w1 = *(const bf16x8*)&buf[(16 + lnm) * 256 + uu];
#pragma unroll
            for (int t = 0; t < 2; t++) {
              acc[t][0] = __builtin_amdgcn_mfma_f32_16x16x32_bf16(w0, efrag[t][ks], acc[t][0], 0, 0, 0);
              acc[t][1] = __builtin_amdgcn_mfma_f32_16x16x32_bf16(w1, efrag[t][ks], acc[t][1], 0, 0, 0);
            }
          }
        } else {
#pragma unroll
          for (int ki = 0; ki < 8; ki++) {
            const int ks = ki ^ 1;
            const int uu = ((ks * 4 + lnq) ^ (lnm & 7)) * 8;
            bf16x8 w0 = *(const bf16x8*)&buf[lnm * 256 + uu];
            bf16x8 w1 = *(const bf16x8*)&buf[(16 + lnm) * 256 + uu];
#pragma unroll
            for (int t = 0; t < 2; t++) {
              acc[t][0] = __builtin_amdgcn_mfma_f32_16x16x32_bf16(w0, efrag[t][ks], acc[t][0], 0, 0, 0);
              acc[t][1] = __builtin_amdgcn_mfma_f32_16x16x32_bf16(w1, efrag[t][ks], acc[t][1], 0, 0, 0);
            }
          }
        }
        __builtin_amdgcn_s_setprio(0);
        cb = nb;
      }
      // ======== kh = 1 : compute chunk q+1 from Wst[cb] ========
      {
        const int nb = (cb == 2) ? 0 : cb + 1;
        if (q + 2 < 128) {
          stageW16(chunk_base(W1g, q + 2), Wst[nb], tid);
          asm volatile("s_waitcnt vmcnt(4)" ::: "memory");  // retires epi + stage(q+1)
        } else {
          asm volatile("s_waitcnt vmcnt(0)" ::: "memory");  // last chunk: drain
        }
        __builtin_amdgcn_s_barrier();
        const u16* buf = Wst[cb];
        __builtin_amdgcn_s_setprio(1);
        if (stg == 0) {
#pragma unroll
          for (int ks = 0; ks < 8; ks++) {
            const int uu = ((ks * 4 + lnq) ^ (lnm & 7)) * 8;
            bf16x8 w0 = *(const bf16x8*)&buf[lnm * 256 + uu];
            bf16x8 w1 = *(const bf16x8*)&buf[(16 + lnm) * 256 + uu];
#pragma unroll
            for (int t = 0; t < 2; t++) {
              acc[t][0] = __builtin_amdgcn_mfma_f32_16x16x32_bf16(w0, efrag[t][8 + ks], acc[t][0], 0, 0, 0);
              acc[t][1] = __builtin_amdgcn_mfma_f32_16x16x32_bf16(w1, efrag[t][8 + ks], acc[t][1], 0, 0, 0);
            }
          }
        } else {
#pragma unroll
          for (int ki = 0; ki < 8; ki++) {
            const int ks = ki ^ 1;
            const int uu = ((ks * 4 + lnq) ^ (lnm & 7)) * 8;
            bf16x8 w0 = *(const bf16x8*)&buf[lnm * 256 + uu];
            bf16x8 w1 = *(const bf16x8*)&buf[(16 + lnm) * 256 + uu];
#pragma unroll
            for (int t = 0; t < 2; t++) {
              acc[t][0] = __builtin_amdgcn_mfma_f32_16x16x32_bf16(w0, efrag[t][8 + ks], acc[t][0], 0, 0, 0);
              acc[t][1] = __builtin_amdgcn_mfma_f32_16x16x32_bf16(w1, efrag[t][8 + ks], acc[t][1], 0, 0, 0);
            }
          }
        }
        __builtin_amdgcn_s_setprio(0);
        cb = nb;
      }
      // ---- epilogue: h1 = relu(acc + b1) -> wave-private h1c rows (packed b64) ----
#pragma unroll
      for (int ct = 0; ct < 2; ct++) {
        float4 bq = ct ? bq1 : bq0;
#pragma unroll
        for (int t = 0; t < 2; t++) {
          union { u16 u[4]; uint2 v; } pk;
          pk.u[0] = f2bf(fmaxf(acc[t][ct][0] + bq.x, 0.f));
          pk.u[1] = f2bf(fmaxf(acc[t][ct][1] + bq.y, 0.f));
          pk.u[2] = f2bf(fmaxf(acc[t][ct][2] + bq.z, 0.f));
          pk.u[3] = f2bf(fmaxf(acc[t][ct][3] + bq.w, 0.f));
          *(uint2*)&h1c[(wave * 32 + t * 16 + lnm) * H1STR + ct * 16 + lnq * 4] = pk.v;
        }
      }
      // ---- GEMM2 partial over this 32-wcol window (wave-private, no barrier) ----
      {
#pragma unroll
        for (int t = 0; t < 2; t++) {
          bf16x8 a2 = *(const bf16x8*)&h1c[(wave * 32 + t * 16 + lnm) * H1STR + lnq * 8];
          oacc[t] = __builtin_amdgcn_mfma_f32_16x16x32_bf16(a2, bw, oacc[t], 0, 0, 0);
        }
      }
    }
    // ---- end of source: sigmoid + alpha-weighted accumulate ----
    {
#pragma unroll
      for (int t = 0; t < 2; t++) {
#pragma unroll
        for (int g = 0; g < 4; g++) {
          float sig = 1.f / (1.f + __expf(-(oacc[t][g] + b2v[j])));
          fin[t][g] += alphS[j][wave * 32 + t * 16 + lnq * 4 + g] * sig;
        }
      }
    }
  }
  // combine partials across the 2 source-groups
  if (lnm < NT) {
#pragma unroll
    for (int t = 0; t < 2; t++) {
#pragma unroll
      for (int g = 0; g < 4; g++) {
        int rg = row0 + wave * 32 + t * 16 + lnq * 4 + g;
        atomicAdd(&out[(size_t)rg * NT + lnm], fin[t][g]);
      }
    }
  }
}

extern "C" void kernel_launch(void* const* d_in, const int* in_sizes, int n_in,
                              void* d_out, int out_size, void* d_ws, size_t ws_size,
                              hipStream_t stream) {
  const float* enc = (const float*)d_in[0];
  const float* mu  = (const float*)d_in[1];
  const float* Us  = (const float*)d_in[2];
  const float* W1  = (const float*)d_in[3];
  const float* b1  = (const float*)d_in[4];
  const float* W2  = (const float*)d_in[5];
  const float* b2  = (const float*)d_in[6];
  float* out = (float*)d_out;
  char* ws = (char*)d_ws;
  u16* W1T    = (u16*)(ws + WS_W1T);
  u16* UcatT  = (u16*)(ws + WS_UCT);
  u16* W2T    = (u16*)(ws + WS_W2T);
  float* cvec = (float*)(ws + WS_CVEC);
  float* alphT = (float*)(ws + WS_ALPH);

  prep<<<2560, dim3(32, 8, 1), 0, stream>>>(W1, W1T, Us, UcatT, W2, W2T, mu, cvec);
  routing<<<512, 256, 0, stream>>>(enc, UcatT, cvec, alphT);
  hipMemsetAsync(out, 0, (size_t)out_size * sizeof(float), stream);
  moe_main<<<512, 256, 0, stream>>>(enc, W1T, W2T, alphT, b1, b2, out);
}